// Round 24
// baseline (70.885 us; speedup 1.0000x reference)
//
#include <hip/hip_runtime.h>
#include <hip/hip_fp16.h>

typedef _Float16 f16x8 __attribute__((ext_vector_type(8)));
typedef float    f32x4 __attribute__((ext_vector_type(4)));
typedef float    f32x2 __attribute__((ext_vector_type(2)));

#define IMG   512
#define NIMG  64
#define NBLK  (NIMG * 16 * 16)   // 16384 blocks; each does one 32x32 tile
#define XST2  52                 // staged row stride (halves); 104 B -> 2-way-free
#define PL2   (42 * XST2)        // plane stride in halves
#define UNITS 1008               // 2 planes * 42 rows * 12 float4-units
#define HTS   36                 // Ht slot stride in halves (72 B, conflict-free)

#define C1F   1.0e-4f
#define C2F   9.0e-4f
#define INVSUM 0.26601174f   // 1 / sum_{k=0..10} exp(-(k-5)^2/4.5)

__device__ __forceinline__ uint2 cvt4h(f32x4 a) {
    __half2 p0 = __floats2half2_rn(a[0], a[1]);
    __half2 p1 = __floats2half2_rn(a[2], a[3]);
    uint2 r; r.x = *reinterpret_cast<uint*>(&p0); r.y = *reinterpret_cast<uint*>(&p1);
    return r;
}

__global__ __launch_bounds__(128, 3)
void ssim_main(const float* __restrict__ x, const float* __restrict__ y,
               float* __restrict__ partial) {
    // Plane 0 = X (rows 0..41), plane 1 = Y: 42 rows x 48 cols (c0-8 .. c0+39).
    __shared__ __align__(16) __half XYp[2 * PL2];           // 8736 B
    // A/B-split Ht: 3 fields x 32 cols x 36; wave-private columns.
    __shared__ __align__(16) __half Ht[3][32][HTS];         // 6912 B
    __shared__ float red[2];

    const int tid  = threadIdx.x;
    const int lane = tid & 63;
    const int wv   = tid >> 6;       // wave 0..1 -> 16-col output strip
    const int l16  = lane & 15;
    const int g16  = lane >> 4;
    const int n0   = wv * 16;

    const int img = blockIdx.z;
    const int by  = blockIdx.y;
    const int r0  = by * 32;
    const int c0  = blockIdx.x * 32;
    const float* xb = x + (size_t)img * IMG * IMG;
    const float* yb = y + (size_t)img * IMG * IMG;

    // ---- Staging: 1008 float4 units over 8x128; walk (12 units/row) ----
    const int row0 = tid / 12;
    const int c40  = tid - row0 * 12;
    float4 st[8];
    {
        int row_u = row0, c4 = c40;
        #pragma unroll
        for (int i = 0; i < 8; ++i) {
            bool valid = (i < 7) | (tid < UNITS - 7 * 128);   // last iter: tid<112
            int  ru = row_u > 83 ? 83 : row_u;
            bool pl = ru >= 42;
            int  rp = pl ? ru - 42 : ru;
            int  gr = r0 - 5 + rp;
            int  gc = c0 - 8 + c4 * 4;            // 32B-aligned, never straddles
            bool ok = valid & ((unsigned)gr < (unsigned)IMG)
                            & ((unsigned)gc <= (unsigned)(IMG - 4));
            const float* src = (pl ? yb : xb) + (size_t)gr * IMG + gc;
            st[i] = ok ? *(const float4*)src : make_float4(0.f, 0.f, 0.f, 0.f);
            c4 += 8; int inc = 10;
            if (c4 >= 12) { c4 -= 12; inc = 11; }
            row_u += inc;
        }
    }

    // ---- Band fragments (overlap the loads) ----
    //  H-pass B[k][n] = w(k - n - 3); V-pass A[r][k] = w(k - r).
    f16x8 WhB, WvA;
    {
        const int d0 = g16 * 8 - l16 - 3;
        _Float16 bv[11];
        #pragma unroll
        for (int j = 0; j < 11; ++j) {
            int d = d0 + j;
            float t = (float)(d - 5);
            float v = __expf(-t * t * (1.0f / 4.5f)) * INVSUM;
            bv[j] = ((unsigned)d <= 10u) ? (_Float16)v : (_Float16)0.0f;
        }
        #pragma unroll
        for (int j = 0; j < 8; ++j) WhB[j] = bv[j];
        #pragma unroll
        for (int j = 0; j < 8; ++j) WvA[j] = bv[j + 3];
    }

    // ---- Write staged data to LDS as fp16 (one float4 -> 4 halves) ----
    {
        int row_u = row0, c4 = c40;
        #pragma unroll
        for (int i = 0; i < 8; ++i) {
            if (i < 7 || tid < UNITS - 7 * 128) {
                int  ru = row_u;                   // valid units: row_u <= 83
                bool pl = ru >= 42;
                int  rp = pl ? ru - 42 : ru;
                __half2 p0 = __floats2half2_rn(st[i].x, st[i].y);
                __half2 p1 = __floats2half2_rn(st[i].z, st[i].w);
                uint2 v; v.x = *reinterpret_cast<uint*>(&p0); v.y = *reinterpret_cast<uint*>(&p1);
                *(uint2*)&XYp[(pl ? PL2 : 0) + rp * XST2 + c4 * 4] = v;
            }
            c4 += 8; int inc = 10;
            if (c4 >= 12) { c4 -= 12; inc = 11; }
            row_u += inc;
        }
    }
    __syncthreads();                     // XYp ready (shared by both waves)

    const int hcol = n0 + l16;
    f32x2 ssum2 = {0.0f, 0.0f};

    // Pass A H: {X, Y, XY} for h-rows [g*16, g*16+16) -> Ht[0..2] at slot sb.
    // H-rows 42..47 are zero-weighted in the V-pass -> clamp staged row to 41.
    auto hpassA = [&](int g, int sb) {
        int srow = g * 16 + l16;
        if (srow > 41) srow = 41;
        int off = srow * XST2 + n0 + g16 * 8;
        f16x8 xf = *(const f16x8*)&XYp[off];
        f16x8 yf = *(const f16x8*)&XYp[PL2 + off];
        f16x8 xy = xf * yf;
        f32x4 z = {0.f, 0.f, 0.f, 0.f};
        f32x4 aX  = __builtin_amdgcn_mfma_f32_16x16x32_f16(xf, WhB, z, 0, 0, 0);
        f32x4 aY  = __builtin_amdgcn_mfma_f32_16x16x32_f16(yf, WhB, z, 0, 0, 0);
        f32x4 aXY = __builtin_amdgcn_mfma_f32_16x16x32_f16(xy, WhB, z, 0, 0, 0);
        int hrow = sb + g16 * 4;     // slot; C layout: col=l16, rows=g16*4+reg
        *(uint2*)&Ht[0][hcol][hrow] = cvt4h(aX);
        *(uint2*)&Ht[1][hcol][hrow] = cvt4h(aY);
        *(uint2*)&Ht[2][hcol][hrow] = cvt4h(aXY);
    };

    // Pass B H: {XX, YY} -> Ht[0..1] (reuses pass-A slots after their V reads;
    // same-wave in-order LDS, wave-private columns).
    auto hpassB = [&](int g, int sb) {
        int srow = g * 16 + l16;
        if (srow > 41) srow = 41;
        int off = srow * XST2 + n0 + g16 * 8;
        f16x8 xf = *(const f16x8*)&XYp[off];
        f16x8 yf = *(const f16x8*)&XYp[PL2 + off];
        f16x8 xx = xf * xf;
        f16x8 yy = yf * yf;
        f32x4 z = {0.f, 0.f, 0.f, 0.f};
        f32x4 aXX = __builtin_amdgcn_mfma_f32_16x16x32_f16(xx, WhB, z, 0, 0, 0);
        f32x4 aYY = __builtin_amdgcn_mfma_f32_16x16x32_f16(yy, WhB, z, 0, 0, 0);
        int hrow = sb + g16 * 4;
        *(uint2*)&Ht[0][hcol][hrow] = cvt4h(aXX);
        *(uint2*)&Ht[1][hcol][hrow] = cvt4h(aYY);
    };

    // Pass A V: window [mt*16, mt*16+32) -> partials for X, Y, XY (in regs).
    auto vpassA = [&](int mt, f32x4& oX, f32x4& oY, f32x4& oXY) {
        int ko = (mt * 16 + g16 * 8) & 31;   // 8-slot groups never straddle the wrap
        f16x8 b0 = *(const f16x8*)&Ht[0][hcol][ko];
        f16x8 b1 = *(const f16x8*)&Ht[1][hcol][ko];
        f16x8 b2 = *(const f16x8*)&Ht[2][hcol][ko];
        f32x4 z = {0.f, 0.f, 0.f, 0.f};
        oX  = __builtin_amdgcn_mfma_f32_16x16x32_f16(WvA, b0, z, 0, 0, 0);
        oY  = __builtin_amdgcn_mfma_f32_16x16x32_f16(WvA, b1, z, 0, 0, 0);
        oXY = __builtin_amdgcn_mfma_f32_16x16x32_f16(WvA, b2, z, 0, 0, 0);
    };

    // Pass B V: window mt -> XX, YY; fuse SSIM epilogue with held A partials.
    auto vpassB = [&](int mt, f32x4 vXm, f32x4 vYm, f32x4 vXYm) {
        int ko = (mt * 16 + g16 * 8) & 31;
        f16x8 b0 = *(const f16x8*)&Ht[0][hcol][ko];
        f16x8 b1 = *(const f16x8*)&Ht[1][hcol][ko];
        f32x4 z = {0.f, 0.f, 0.f, 0.f};
        f32x4 cXX = __builtin_amdgcn_mfma_f32_16x16x32_f16(WvA, b0, z, 0, 0, 0);
        f32x4 cYY = __builtin_amdgcn_mfma_f32_16x16x32_f16(WvA, b1, z, 0, 0, 0);
        #pragma unroll
        for (int h = 0; h < 2; ++h) {
            f32x2 mx  = {vXm [2*h], vXm [2*h+1]};
            f32x2 my  = {vYm [2*h], vYm [2*h+1]};
            f32x2 exx = {cXX [2*h], cXX [2*h+1]};
            f32x2 eyy = {cYY [2*h], cYY [2*h+1]};
            f32x2 exy = {vXYm[2*h], vXYm[2*h+1]};
            f32x2 mxx = mx * mx, myy = my * my, mxy = mx * my;
            f32x2 vx  = exx - mxx;
            f32x2 vy  = eyy - myy;
            f32x2 vxy = exy - mxy;
            f32x2 num = (2.0f * mxy + C1F) * (2.0f * vxy + C2F);
            f32x2 den = (mxx + myy + C1F) * (vx + vy + C2F);
            f32x2 r;
            r[0] = __builtin_amdgcn_rcpf(den[0]);
            r[1] = __builtin_amdgcn_rcpf(den[1]);
            ssum2 += num * r;
        }
    };

    // ---- One tile: pass A ring, then pass B ring (same slots) ----
    {
        f32x4 cX0, cY0, cXY0, cX1, cY1, cXY1;
        hpassA(0, 0); hpassA(1, 16);
        vpassA(0, cX0, cY0, cXY0);
        hpassA(2, 0);
        vpassA(1, cX1, cY1, cXY1);
        hpassB(0, 0); hpassB(1, 16);
        vpassB(0, cX0, cY0, cXY0);
        hpassB(2, 0);
        vpassB(1, cX1, cY1, cXY1);
    }

    // ---- Block reduction (deterministic) ----
    float ssum = ssum2[0] + ssum2[1];
    #pragma unroll
    for (int off = 32; off > 0; off >>= 1)
        ssum += __shfl_down(ssum, off, 64);
    if ((tid & 63) == 0) red[tid >> 6] = ssum;
    __syncthreads();
    if (tid == 0) {
        int bi = (img * gridDim.y + by) * gridDim.x + blockIdx.x;
        partial[bi] = red[0] + red[1];
    }
}

__global__ __launch_bounds__(1024)
void ssim_final(const float* __restrict__ partial, float* __restrict__ out) {
    __shared__ float red[16];
    float s = 0.0f;
    for (int i = threadIdx.x; i < NBLK; i += 1024) s += partial[i];
    #pragma unroll
    for (int off = 32; off > 0; off >>= 1)
        s += __shfl_down(s, off, 64);
    if ((threadIdx.x & 63) == 0) red[threadIdx.x >> 6] = s;
    __syncthreads();
    if (threadIdx.x == 0) {
        float tot = 0.0f;
        #pragma unroll
        for (int i = 0; i < 16; ++i) tot += red[i];
        out[0] = 1.0f - tot * (1.0f / 16777216.0f);
    }
}

extern "C" void kernel_launch(void* const* d_in, const int* in_sizes, int n_in,
                              void* d_out, int out_size, void* d_ws, size_t ws_size,
                              hipStream_t stream) {
    const float* x = (const float*)d_in[0];
    const float* y = (const float*)d_in[1];
    float* out     = (float*)d_out;
    float* partial = (float*)d_ws;   // NBLK floats = 64 KB

    dim3 grid(IMG / 32, IMG / 32, NIMG);   // (16, 16, 64); 1 tile per block
    ssim_main<<<grid, 128, 0, stream>>>(x, y, partial);
    ssim_final<<<1, 1024, 0, stream>>>(partial, out);
}

// Round 25
// 46.577 us; speedup vs baseline: 1.5219x; 1.5219x over previous
//
#include <hip/hip_runtime.h>
#include <hip/hip_fp16.h>

typedef _Float16 f16x8 __attribute__((ext_vector_type(8)));
typedef float    f32x4 __attribute__((ext_vector_type(4)));
typedef float    f32x2 __attribute__((ext_vector_type(2)));

#define IMG   512
#define NIMG  64
#define TS_C  64
#define NBLK  (NIMG * 8 * 8)     // 4096 blocks; each does 2 row-tiles of 32
#define XST   88     // staged row stride in halves (176 B: 2-way-free b128 reads)
#define HTS   36     // Ht slot stride in halves (72 B: conflict-free b128 reads)
#define SROWS 42     // staged rows per plane (image rows r0-5 .. r0+36)

#define C1F   1.0e-4f
#define C2F   9.0e-4f
#define INVSUM 0.26601174f   // 1 / sum_{k=0..10} exp(-(k-5)^2/4.5)

__device__ __forceinline__ uint2 cvt4h(f32x4 a) {
    __half2 p0 = __floats2half2_rn(a[0], a[1]);
    __half2 p1 = __floats2half2_rn(a[2], a[3]);
    uint2 r; r.x = *reinterpret_cast<uint*>(&p0); r.y = *reinterpret_cast<uint*>(&p1);
    return r;
}

__global__ __launch_bounds__(256, 3)
void ssim_main(const float* __restrict__ x, const float* __restrict__ y,
               float* __restrict__ partial) {
    // Plane 0 = X (rows 0..41), plane 1 = Y (rows 42..83) — one contiguous array.
    __shared__ __align__(16) __half XYp[2 * SROWS * XST];   // 14784 B
    // Ring-buffered H fields: 32 slots (slot = h_row & 31).
    __shared__ __align__(16) __half Ht[5][TS_C][HTS];       // 23040 B
    __shared__ float red[4];

    const int tid  = threadIdx.x;
    const int lane = tid & 63;
    const int wv   = tid >> 6;       // wave 0..3 -> 16-col output strip
    const int l16  = lane & 15;
    const int g16  = lane >> 4;
    const int n0   = wv * 16;

    const int img = blockIdx.z;
    const int by  = blockIdx.y;
    const int c0  = blockIdx.x * TS_C;
    const float* xb = x + (size_t)img * IMG * IMG;
    const float* yb = y + (size_t)img * IMG * IMG;

    // ---- Staging walk base (20 float4-units per combined row; 2*42*20 = 1680) ----
    const int row0 = tid / 20;
    const int c40  = tid - row0 * 20;

    auto stage_load = [&](int r0, float4* st) {
        bool interior = (r0 >= 8) & (r0 <= IMG - 37) & (c0 >= 8) & (c0 <= IMG - 72);
        int row_u = row0, c4 = c40;
        #pragma unroll
        for (int i = 0; i < 7; ++i) {
            int  ru = row_u > 83 ? 83 : row_u;      // clamp for i=6 invalid threads
            bool ya = ru >= SROWS;
            int  rp = ya ? ru - SROWS : ru;
            int  gr = r0 - 5 + rp;
            int  gc = c0 - 8 + c4 * 4;              // float4 never straddles [0,512)
            const float* src = (ya ? yb : xb) + (size_t)gr * IMG + gc;
            if (interior) {
                st[i] = *(const float4*)src;        // always in-bounds
            } else {
                bool valid = (i < 6) | (tid < 144);
                bool ok = valid & ((unsigned)gr < (unsigned)IMG) & ((unsigned)gc < (unsigned)IMG);
                st[i] = ok ? *(const float4*)src : make_float4(0.f, 0.f, 0.f, 0.f);
            }
            c4 += 16; int inc = 12;
            if (c4 >= 20) { c4 -= 20; inc = 13; }
            row_u += inc;
        }
    };

    auto stage_write = [&](const float4* st) {
        int row_u = row0, c4 = c40;
        #pragma unroll
        for (int i = 0; i < 7; ++i) {
            if (i < 6 || tid < 144) {
                __half2 p0 = __floats2half2_rn(st[i].x, st[i].y);
                __half2 p1 = __floats2half2_rn(st[i].z, st[i].w);
                uint2 v; v.x = *reinterpret_cast<uint*>(&p0); v.y = *reinterpret_cast<uint*>(&p1);
                *(uint2*)&XYp[row_u * XST + c4 * 4] = v;
            }
            c4 += 16; int inc = 12;
            if (c4 >= 20) { c4 -= 20; inc = 13; }
            row_u += inc;
        }
    };

    const int hcol = n0 + l16;
    f32x2 ssum2 = {0.0f, 0.0f};
    f16x8 WhB, WvA;

    // H pass for h-rows [g*16, g*16+16); writes slot base sb.
    // H-rows 42..47 are zero-weighted in the V-pass -> clamp staged row to 41.
    auto hpass = [&](int g, int sb) {
        int srow = g * 16 + l16;
        if (srow > SROWS - 1) srow = SROWS - 1;
        int off = srow * XST + n0 + g16 * 8;
        f16x8 xf = *(const f16x8*)&XYp[off];
        f16x8 yf = *(const f16x8*)&XYp[SROWS * XST + off];
        f16x8 xx = xf * xf;
        f16x8 yy = yf * yf;
        f16x8 xy = xf * yf;
        f32x4 z = {0.f, 0.f, 0.f, 0.f};
        f32x4 aX  = __builtin_amdgcn_mfma_f32_16x16x32_f16(xf, WhB, z, 0, 0, 0);
        f32x4 aY  = __builtin_amdgcn_mfma_f32_16x16x32_f16(yf, WhB, z, 0, 0, 0);
        f32x4 aXX = __builtin_amdgcn_mfma_f32_16x16x32_f16(xx, WhB, z, 0, 0, 0);
        f32x4 aYY = __builtin_amdgcn_mfma_f32_16x16x32_f16(yy, WhB, z, 0, 0, 0);
        f32x4 aXY = __builtin_amdgcn_mfma_f32_16x16x32_f16(xy, WhB, z, 0, 0, 0);
        int hrow = sb + g16 * 4;     // slot; C layout: col=l16, rows=g16*4+reg
        *(uint2*)&Ht[0][hcol][hrow] = cvt4h(aX);
        *(uint2*)&Ht[1][hcol][hrow] = cvt4h(aY);
        *(uint2*)&Ht[2][hcol][hrow] = cvt4h(aXX);
        *(uint2*)&Ht[3][hcol][hrow] = cvt4h(aYY);
        *(uint2*)&Ht[4][hcol][hrow] = cvt4h(aXY);
    };

    // V pass over h-row window [mt*16, mt*16+32): slots (mt*16 + g16*8) & 31.
    auto vpass = [&](int mt) {
        int ko = (mt * 16 + g16 * 8) & 31;   // 8-slot groups never straddle the wrap
        f16x8 b0 = *(const f16x8*)&Ht[0][hcol][ko];
        f16x8 b1 = *(const f16x8*)&Ht[1][hcol][ko];
        f16x8 b2 = *(const f16x8*)&Ht[2][hcol][ko];
        f16x8 b3 = *(const f16x8*)&Ht[3][hcol][ko];
        f16x8 b4 = *(const f16x8*)&Ht[4][hcol][ko];
        f32x4 z = {0.f, 0.f, 0.f, 0.f};
        f32x4 cX  = __builtin_amdgcn_mfma_f32_16x16x32_f16(WvA, b0, z, 0, 0, 0);
        f32x4 cY  = __builtin_amdgcn_mfma_f32_16x16x32_f16(WvA, b1, z, 0, 0, 0);
        f32x4 cXX = __builtin_amdgcn_mfma_f32_16x16x32_f16(WvA, b2, z, 0, 0, 0);
        f32x4 cYY = __builtin_amdgcn_mfma_f32_16x16x32_f16(WvA, b3, z, 0, 0, 0);
        f32x4 cXY = __builtin_amdgcn_mfma_f32_16x16x32_f16(WvA, b4, z, 0, 0, 0);
        // Packed-fp32 epilogue (v_pk_*): 2 px per op.
        #pragma unroll
        for (int h = 0; h < 2; ++h) {
            f32x2 mx  = {cX [2*h], cX [2*h+1]};
            f32x2 my  = {cY [2*h], cY [2*h+1]};
            f32x2 exx = {cXX[2*h], cXX[2*h+1]};
            f32x2 eyy = {cYY[2*h], cYY[2*h+1]};
            f32x2 exy = {cXY[2*h], cXY[2*h+1]};
            f32x2 mxx = mx * mx, myy = my * my, mxy = mx * my;
            f32x2 vx  = exx - mxx;
            f32x2 vy  = eyy - myy;
            f32x2 vxy = exy - mxy;
            f32x2 num = (2.0f * mxy + C1F) * (2.0f * vxy + C2F);
            f32x2 den = (mxx + myy + C1F) * (vx + vy + C2F);
            f32x2 r;
            r[0] = __builtin_amdgcn_rcpf(den[0]);
            r[1] = __builtin_amdgcn_rcpf(den[1]);
            ssum2 += num * r;
        }
    };

    auto compute = [&]() {
        // Ring schedule (wave-private Ht columns -> no barriers inside)
        hpass(0, 0); hpass(1, 16); vpass(0); hpass(2, 0); vpass(1);
    };

    // ================== two row-tiles per block ==================
    const int r0a = by * 64;
    const int r0b = by * 64 + 32;
    float4 st0[7], st1[7];

    stage_load(r0a, st0);                // issue t0 loads
    stage_load(r0b, st1);                // issue t1 loads (14 in flight)

    // Band fragments, computed in-register (overlaps the loads):
    //  H-pass B[k][n] = w(k - n - 3), k=g16*8+j, n=l16  -> d = d0 + j
    //  V-pass A[r][k] = w(k - r),     r=l16, k=g16*8+j  -> d = d0 + j + 3
    {
        const int d0 = g16 * 8 - l16 - 3;
        _Float16 bv[11];
        #pragma unroll
        for (int j = 0; j < 11; ++j) {
            int d = d0 + j;
            float t = (float)(d - 5);
            float v = __expf(-t * t * (1.0f / 4.5f)) * INVSUM;
            bv[j] = ((unsigned)d <= 10u) ? (_Float16)v : (_Float16)0.0f;
        }
        #pragma unroll
        for (int j = 0; j < 8; ++j) WhB[j] = bv[j];
        #pragma unroll
        for (int j = 0; j < 8; ++j) WvA[j] = bv[j + 3];
    }

    stage_write(st0);                    // waits only t0's 7 loads
    __syncthreads();                     // XYp(t0) ready

    compute();                           // tile 0
    __syncthreads();                     // tile0 XYp reads done
    stage_write(st1);
    __syncthreads();                     // XYp(t1) ready
    compute();                           // tile 1

    // ---- Block reduction (deterministic) ----
    float ssum = ssum2[0] + ssum2[1];
    #pragma unroll
    for (int off = 32; off > 0; off >>= 1)
        ssum += __shfl_down(ssum, off, 64);
    if ((tid & 63) == 0) red[tid >> 6] = ssum;
    __syncthreads();
    if (tid == 0) {
        float tot = red[0] + red[1] + red[2] + red[3];
        int bi = (img * gridDim.y + by) * gridDim.x + blockIdx.x;
        partial[bi] = tot;
    }
}

__global__ __launch_bounds__(1024)
void ssim_final(const float* __restrict__ partial, float* __restrict__ out) {
    __shared__ float red[16];
    float s = 0.0f;
    for (int i = threadIdx.x; i < NBLK; i += 1024) s += partial[i];
    #pragma unroll
    for (int off = 32; off > 0; off >>= 1)
        s += __shfl_down(s, off, 64);
    if ((threadIdx.x & 63) == 0) red[threadIdx.x >> 6] = s;
    __syncthreads();
    if (threadIdx.x == 0) {
        float tot = 0.0f;
        #pragma unroll
        for (int i = 0; i < 16; ++i) tot += red[i];
        out[0] = 1.0f - tot * (1.0f / 16777216.0f);
    }
}

extern "C" void kernel_launch(void* const* d_in, const int* in_sizes, int n_in,
                              void* d_out, int out_size, void* d_ws, size_t ws_size,
                              hipStream_t stream) {
    const float* x = (const float*)d_in[0];
    const float* y = (const float*)d_in[1];
    float* out     = (float*)d_out;
    float* partial = (float*)d_ws;   // NBLK floats = 16 KB

    dim3 grid(IMG / TS_C, 8, NIMG);   // (8, 8, 64); each block = 2 row-tiles
    ssim_main<<<grid, 256, 0, stream>>>(x, y, partial);
    ssim_final<<<1, 1024, 0, stream>>>(partial, out);
}